// Round 10
// baseline (796.547 us; speedup 1.0000x reference)
//
#include <hip/hip_runtime.h>

#define N_NODES 100000
#define E_EDGES 1600000
#define E_TOT   1700000   // edges + self loops
#define FDIM    128       // F_IN and HEADS*HID
#define C2      10        // classes
#define YPAD    16        // yl/yr row stride (one 64B line)
#define NEG     0.2f
#define LOG2E   1.44269504088896f
#define PCLAMP  80.0f

typedef __attribute__((ext_vector_type(8))) short short8;
typedef __attribute__((ext_vector_type(4))) float f32x4;

// 16-lane row reduction via DPP (pure VALU, no LDS pipe)
template <int CTRL>
__device__ __forceinline__ float dpp_add(float x) {
  return x + __int_as_float(
      __builtin_amdgcn_update_dpp(0, __float_as_int(x), CTRL, 0xF, 0xF, true));
}
__device__ __forceinline__ float row16_sum(float p) {
  p = dpp_add<0xB1>(p);
  p = dpp_add<0x4E>(p);
  p = dpp_add<0x141>(p);
  p = dpp_add<0x140>(p);
  return p;
}

// fp32 -> bf16 (round-nearest-even), and packed bf16x2 -> float2
__device__ __forceinline__ unsigned short f2bf(float f) {
  unsigned int u = __float_as_uint(f);
  u += 0x7FFFu + ((u >> 16) & 1u);
  return (unsigned short)(u >> 16);
}
__device__ __forceinline__ float2 up2(unsigned int v) {
  return make_float2(__uint_as_float(v << 16), __uint_as_float(v & 0xFFFF0000u));
}

// ---------------- CSR build ----------------
__global__ __launch_bounds__(256) void k_deg(const int* __restrict__ ei, int* __restrict__ cnt,
                                             int* __restrict__ epos) {
  int tid = blockIdx.x * 256 + threadIdx.x;
  if (tid >= E_TOT) return;
  int d = (tid < E_EDGES) ? ei[E_EDGES + tid] : (tid - E_EDGES);
  epos[tid] = atomicAdd(&cnt[d], 1);
}

#define SCAN_ITEMS 8
#define SCAN_CHUNK 2048
#define SCAN_NBLK  ((N_NODES + SCAN_CHUNK - 1) / SCAN_CHUNK)   // 49

__global__ __launch_bounds__(256) void k_scan1(const int* __restrict__ cnt, int* __restrict__ bsum) {
  int b = blockIdx.x, t = threadIdx.x;
  int base = b * SCAN_CHUNK + t * SCAN_ITEMS;
  int s = 0;
#pragma unroll
  for (int i = 0; i < SCAN_ITEMS; i++) {
    int idx = base + i;
    if (idx < N_NODES) s += cnt[idx];
  }
  __shared__ int sd[256];
  sd[t] = s; __syncthreads();
  for (int o = 128; o > 0; o >>= 1) {
    if (t < o) sd[t] += sd[t + o];
    __syncthreads();
  }
  if (t == 0) bsum[b] = sd[0];
}

__global__ __launch_bounds__(64) void k_scan2(const int* __restrict__ bsum, int* __restrict__ boff) {
  int t = threadIdx.x;
  int v = (t < SCAN_NBLK) ? bsum[t] : 0;
  int orig = v;
  for (int o = 1; o < 64; o <<= 1) {
    int u = __shfl_up(v, o);
    if (t >= o) v += u;
  }
  if (t < SCAN_NBLK) boff[t] = v - orig;
}

__global__ __launch_bounds__(256) void k_scan3(const int* __restrict__ cnt, const int* __restrict__ boff,
                                               int* __restrict__ row_ptr) {
  int b = blockIdx.x, t = threadIdx.x;
  int base = b * SCAN_CHUNK + t * SCAN_ITEMS;
  int vals[SCAN_ITEMS]; int ts = 0;
#pragma unroll
  for (int i = 0; i < SCAN_ITEMS; i++) {
    int idx = base + i;
    vals[i] = (idx < N_NODES) ? cnt[idx] : 0;
    ts += vals[i];
  }
  __shared__ int sd[256];
  sd[t] = ts; __syncthreads();
  for (int o = 1; o < 256; o <<= 1) {
    int v = 0;
    if (t >= o) v = sd[t - o];
    __syncthreads();
    sd[t] += v;
    __syncthreads();
  }
  int run = boff[b] + sd[t] - ts;
#pragma unroll
  for (int i = 0; i < SCAN_ITEMS; i++) {
    int idx = base + i;
    if (idx < N_NODES) row_ptr[idx] = run;
    run += vals[i];
  }
  if (b == 0 && t == 0) row_ptr[N_NODES] = E_TOT;
}

__global__ __launch_bounds__(256) void k_scatter(const int* __restrict__ ei,
                                                 const int* __restrict__ row_ptr,
                                                 const int* __restrict__ epos,
                                                 int* __restrict__ colA) {
  int tid = blockIdx.x * 256 + threadIdx.x;
  if (tid >= E_TOT) return;
  int s, d;
  if (tid < E_EDGES) { s = ei[tid]; d = ei[E_EDGES + tid]; }
  else { s = tid - E_EDGES; d = s; }
  colA[row_ptr[d] + epos[tid]] = s;
}

// Canonicalize CSR rows (deterministic FP accumulation order every call).
__global__ __launch_bounds__(256) void k_sort(const int* __restrict__ row_ptr, int* __restrict__ colA) {
  int node = blockIdx.x * 4 + (threadIdx.x >> 6);
  if (node >= N_NODES) return;
  int lane = threadIdx.x & 63;
  int beg = row_ptr[node], end = row_ptr[node + 1];
  int deg = end - beg;
  if (deg <= 1) return;
  if (deg <= 64) {
    int v = (lane < deg) ? colA[beg + lane] : 0x7FFFFFFF;
#pragma unroll
    for (int k = 2; k <= 64; k <<= 1) {
#pragma unroll
      for (int j = k >> 1; j > 0; j >>= 1) {
        int other = __shfl_xor(v, j);
        bool up = ((lane & k) == 0);
        bool lower = ((lane & j) == 0);
        int mn = min(v, other), mx = max(v, other);
        v = (lower == up) ? mn : mx;
      }
    }
    if (lane < deg) colA[beg + lane] = v;
  } else if (lane == 0) {
    for (int i = beg + 1; i < end; i++) {
      int v = colA[i];
      int j = i - 1;
      while (j >= beg && colA[j] > v) { colA[j + 1] = colA[j]; j--; }
      colA[j + 1] = v;
    }
  }
}

// ---------------- prep: W1l|W1r -> transposed bf16 [256][128] ----------------
__global__ __launch_bounds__(256) void k_wt(const float* __restrict__ W1l, const float* __restrict__ W1r,
                                            unsigned short* __restrict__ Wt) {
  int t = blockIdx.x * 256 + threadIdx.x;
  if (t >= 256 * 128) return;
  int n = t & 255, k = t >> 8;
  float v = (n < 128) ? W1l[k * 128 + n] : W1r[k * 128 + (n - 128)];
  Wt[n * 128 + k] = f2bf(v);   // B^T layout: row n, contiguous k
}

// ---------------- Layer-1 GEMM via MFMA: [Hl|Hr] = x @ [W1l|W1r] (bf16 in, fp32 acc) ----------------
__global__ __launch_bounds__(256) void k_gemm1(const float* __restrict__ x,
                                               const unsigned short* __restrict__ Wt,
                                               unsigned short* __restrict__ Hlb,
                                               unsigned short* __restrict__ Hrb) {
  int w = threadIdx.x >> 6, lane = threadIdx.x & 63;
  int m = lane & 15, quad = lane >> 4;
  int row0 = blockIdx.x * 64 + w * 16;
  int arow = row0 + m;
  short8 A[4];
  bool aok = arow < N_NODES;
  const float4* ap = (const float4*)(x + (size_t)arow * FDIM + quad * 8);
#pragma unroll
  for (int c = 0; c < 4; c++) {
    short8 a = {};
    if (aok) {
      float4 v0 = ap[c * 8 + 0];
      float4 v1 = ap[c * 8 + 1];
      a[0] = (short)f2bf(v0.x); a[1] = (short)f2bf(v0.y);
      a[2] = (short)f2bf(v0.z); a[3] = (short)f2bf(v0.w);
      a[4] = (short)f2bf(v1.x); a[5] = (short)f2bf(v1.y);
      a[6] = (short)f2bf(v1.z); a[7] = (short)f2bf(v1.w);
    }
    A[c] = a;
  }

  int orow = row0 + quad * 4;
#pragma unroll
  for (int t0 = 0; t0 < 16; t0++) {
    const short8* bp = (const short8*)(Wt + (size_t)(t0 * 16 + m) * 128 + quad * 8);
    f32x4 acc = {0.f, 0.f, 0.f, 0.f};
#pragma unroll
    for (int c = 0; c < 4; c++)
      acc = __builtin_amdgcn_mfma_f32_16x16x32_bf16(A[c], bp[c * 4], acc, 0, 0, 0);
    int n0 = t0 * 16;
    unsigned short* dst = (n0 < 128) ? Hlb : Hrb;
    int col = (n0 < 128) ? n0 + m : (n0 - 128) + m;
#pragma unroll
    for (int r = 0; r < 4; r++) {
      int row = orow + r;
      if (row < N_NODES) dst[(size_t)row * FDIM + col] = f2bf(acc[r]);
    }
  }
}

// ---------------- Layer-1 aggregation + fused layer-2 transform ----------------
// One WAVE owns 4 consecutive nodes and streams their concatenated edge range
// in 8-edge chunks with double-buffered value regs + idx prefetch: loads for
// chunk k+1 are issued BEFORE chunk k is consumed, so gathers stay in flight
// across node boundaries (boundaries are wave-uniform). Consumption order per
// node is unchanged -> bit-identical. W2 staged transposed in LDS per block.
__global__ __launch_bounds__(256) void k_agg1(const unsigned short* __restrict__ Hlb,
                                              const unsigned short* __restrict__ Hrb,
                                              const int* __restrict__ row_ptr, const int* __restrict__ colA,
                                              const float* __restrict__ att, const float* __restrict__ bias,
                                              const float* __restrict__ W2l, const float* __restrict__ W2r,
                                              float* __restrict__ yl, float* __restrict__ yr) {
  __shared__ float hsh[4][FDIM];
  __shared__ float Wlds[20 * 132];   // [cc][k], stride 132 breaks bank alignment
  for (int idx = threadIdx.x; idx < 20 * 128; idx += 256) {
    int cc = idx >> 7, k = idx & 127;
    Wlds[cc * 132 + k] = (cc < C2) ? W2l[k * C2 + cc] : W2r[k * C2 + (cc - C2)];
  }
  __syncthreads();

  int w = threadIdx.x >> 6;
  int lane = threadIdx.x & 63;
  int nbase = (blockIdx.x * 4 + w) * 4;
  if (nbase >= N_NODES) return;
  int nvalid = (N_NODES - nbase < 4) ? (N_NODES - nbase) : 4;
  int c0 = 2 * lane;
  const unsigned int* Hl32 = (const unsigned int*)Hlb;
  const unsigned int* Hr32 = (const unsigned int*)Hrb;
  float a0 = att[c0] * LOG2E;
  float a1 = att[c0 + 1] * LOG2E;
  float b0 = bias[c0], b1 = bias[c0 + 1];

  int j0   = row_ptr[nbase];
  int e0   = row_ptr[nbase + 1];
  int e1   = row_ptr[(nbase + 2 < N_NODES) ? nbase + 2 : N_NODES];
  int e2   = row_ptr[(nbase + 3 < N_NODES) ? nbase + 3 : N_NODES];
  int e3   = row_ptr[(nbase + 4 < N_NODES) ? nbase + 4 : N_NODES];
  int jend = e3;

  float2 xr0 = up2(Hr32[((size_t)nbase << 6) + lane]);
  float2 xr1 = up2(Hr32[((size_t)(nbase + ((nvalid > 1) ? 1 : 0)) << 6) + lane]);
  float2 xr2 = up2(Hr32[((size_t)(nbase + ((nvalid > 2) ? 2 : 0)) << 6) + lane]);
  float2 xr3 = up2(Hr32[((size_t)(nbase + ((nvalid > 3) ? 3 : 0)) << 6) + lane]);

  int cur = 0;
  int ecur = e0;
  float2 xrc = xr0;
  float l = 0.f, ax = 0.f, ay = 0.f;

  auto finalize = [&]() {
    float inv = 1.f / l;
    float ox = fmaxf(fmaf(ax, inv, b0), 0.f);   // fused ReLU
    float oy = fmaxf(fmaf(ay, inv, b1), 0.f);
    hsh[w][c0] = ox; hsh[w][c0 + 1] = oy;       // intra-wave LDS RAW: in-order
    int node = nbase + cur;
    if (lane < 2 * C2) {
      float acc = 0.f;
      const float4* h4 = (const float4*)hsh[w];
      const float4* wrow = (const float4*)&Wlds[lane * 132];
#pragma unroll
      for (int k4 = 0; k4 < 32; k4++) {
        float4 hv = h4[k4];
        float4 wv = wrow[k4];
        acc = fmaf(hv.x, wv.x, acc);
        acc = fmaf(hv.y, wv.y, acc);
        acc = fmaf(hv.z, wv.z, acc);
        acc = fmaf(hv.w, wv.w, acc);
      }
      bool isl = lane < C2;
      float* Y = isl ? yl : yr;
      int cc = isl ? lane : lane - C2;
      Y[(size_t)node * YPAD + cc] = acc;
    }
    l = 0.f; ax = 0.f; ay = 0.f;
    cur++;
    ecur = (cur == 1) ? e1 : (cur == 2) ? e2 : e3;
    xrc  = (cur == 1) ? xr1 : (cur == 2) ? xr2 : xr3;
  };

  auto update = [&](unsigned int v) {
    float2 xl = up2(v);
    float tx = xl.x + xrc.x, ty = xl.y + xrc.y;
    tx = tx > 0.f ? tx : NEG * tx;
    ty = ty > 0.f ? ty : NEG * ty;
    float p = row16_sum(fmaf(a0, tx, a1 * ty));
    float ww = __builtin_amdgcn_exp2f(fminf(p, PCLAMP));
    l  += ww;
    ax = fmaf(ww, xl.x, ax);
    ay = fmaf(ww, xl.y, ay);
  };

  int ia[8], ib[8];
  unsigned int va[8], vb[8];

  auto loadIdx = [&](int* id, int jc) {
#pragma unroll
    for (int i = 0; i < 8; i++) {
      if (jc + i < jend) id[i] = colA[jc + i]; else id[i] = 0;
    }
  };
  auto loadVal = [&](unsigned int* vv, const int* id, int jc) {
#pragma unroll
    for (int i = 0; i < 8; i++) {
      if (jc + i < jend) vv[i] = Hl32[((size_t)id[i] << 6) + lane]; else vv[i] = 0u;
    }
  };
  auto consume = [&](const unsigned int* vv, int jc) {
#pragma unroll
    for (int i = 0; i < 8; i++) {
      int jj = jc + i;
      if (jj < jend) {
        if (jj == ecur) finalize();   // wave-uniform branch
        update(vv[i]);
      }
    }
  };

  // software pipeline: vals double-buffered, idx two chunks ahead
  loadIdx(ia, j0);
  loadVal(va, ia, j0);
  loadIdx(ib, j0 + 8);
  bool flip = false;
  for (int jc = j0; jc < jend; jc += 8) {
    if (!flip) {
      loadVal(vb, ib, jc + 8);
      loadIdx(ia, jc + 16);
      consume(va, jc);
    } else {
      loadVal(va, ia, jc + 8);
      loadIdx(ib, jc + 16);
      consume(vb, jc);
    }
    flip = !flip;
  }
  finalize();   // last pending node (deg>=1 guarantees exactly one remains)
}

// ---------------- Layer-2 aggregation: 16-lane group per node ----------------
__global__ __launch_bounds__(256) void k_agg2(const float* __restrict__ yl, const float* __restrict__ yr,
                                              const int* __restrict__ row_ptr, const int* __restrict__ colA,
                                              const float* __restrict__ att, const float* __restrict__ bias,
                                              float* __restrict__ outp) {
  int node = blockIdx.x * 16 + (threadIdx.x >> 4);
  if (node >= N_NODES) return;
  int lane = threadIdx.x & 15;
  bool act = lane < C2;
  float xr = act ? yr[(size_t)node * YPAD + lane] : 0.f;
  float a  = act ? att[lane] * LOG2E : 0.f;
  int beg = row_ptr[node], end = row_ptr[node + 1];
  float l = 0.f, acc = 0.f;
  const float* ylL = yl + (act ? lane : 0);

  auto update = [&](float xl) {
    float t = xl + xr;
    t = t > 0.f ? t : NEG * t;
    float p = row16_sum(a * t);
    float w = __builtin_amdgcn_exp2f(fminf(p, PCLAMP));
    l += w;
    acc = fmaf(w, xl, acc);
  };

  int j = beg;
  for (; j + 8 <= end; j += 8) {
    float x0 = act ? ylL[(size_t)colA[j + 0] << 4] : 0.f;
    float x1 = act ? ylL[(size_t)colA[j + 1] << 4] : 0.f;
    float x2 = act ? ylL[(size_t)colA[j + 2] << 4] : 0.f;
    float x3 = act ? ylL[(size_t)colA[j + 3] << 4] : 0.f;
    float x4 = act ? ylL[(size_t)colA[j + 4] << 4] : 0.f;
    float x5 = act ? ylL[(size_t)colA[j + 5] << 4] : 0.f;
    float x6 = act ? ylL[(size_t)colA[j + 6] << 4] : 0.f;
    float x7 = act ? ylL[(size_t)colA[j + 7] << 4] : 0.f;
    update(x0); update(x1); update(x2); update(x3);
    update(x4); update(x5); update(x6); update(x7);
  }
  for (; j < end; j++) {
    float x0 = act ? ylL[(size_t)colA[j] << 4] : 0.f;
    update(x0);
  }
  if (act) outp[(size_t)node * C2 + lane] = acc / l + bias[lane];
}

extern "C" void kernel_launch(void* const* d_in, const int* in_sizes, int n_in,
                              void* d_out, int out_size, void* d_ws, size_t ws_size,
                              hipStream_t stream) {
  const float* x    = (const float*)d_in[0];
  const int*   ei   = (const int*)d_in[1];
  const float* W1l  = (const float*)d_in[2];
  const float* W1r  = (const float*)d_in[3];
  const float* att1 = (const float*)d_in[4];
  const float* b1   = (const float*)d_in[5];
  const float* W2l  = (const float*)d_in[6];
  const float* W2r  = (const float*)d_in[7];
  const float* att2 = (const float*)d_in[8];
  const float* b2   = (const float*)d_in[9];
  float* out = (float*)d_out;

  char* ws = (char*)d_ws;
  size_t off = 0;
  auto take = [&](size_t bytes) -> char* {
    char* p = ws + off;
    off = (off + bytes + 511) & ~(size_t)511;
    return p;
  };
  unsigned short* Hlb = (unsigned short*)take((size_t)N_NODES * FDIM * sizeof(unsigned short)); // 25.6 MB
  unsigned short* Hrb = (unsigned short*)take((size_t)N_NODES * FDIM * sizeof(unsigned short)); // 25.6 MB
  unsigned short* Wt  = (unsigned short*)take((size_t)256 * 128 * sizeof(unsigned short));      // 64 KB
  float* yl      = (float*)take((size_t)N_NODES * YPAD * sizeof(float));   // 6.4 MB
  float* yr      = (float*)take((size_t)N_NODES * YPAD * sizeof(float));   // 6.4 MB
  int*   cnt     = (int*)take((size_t)N_NODES * sizeof(int));
  int*   row_ptr = (int*)take((size_t)(N_NODES + 1) * sizeof(int));
  int*   colA    = (int*)take((size_t)E_TOT * sizeof(int));
  int*   epos    = (int*)take((size_t)E_TOT * sizeof(int));
  int*   bsum    = (int*)take(256);
  int*   boff    = (int*)take(256);
  if (off > ws_size) return;

  (void)hipMemsetAsync(cnt, 0, (size_t)N_NODES * sizeof(int), stream);
  k_deg    <<<(E_TOT + 255) / 256, 256, 0, stream>>>(ei, cnt, epos);
  k_scan1  <<<SCAN_NBLK, 256, 0, stream>>>(cnt, bsum);
  k_scan2  <<<1, 64, 0, stream>>>(bsum, boff);
  k_scan3  <<<SCAN_NBLK, 256, 0, stream>>>(cnt, boff, row_ptr);
  k_scatter<<<(E_TOT + 255) / 256, 256, 0, stream>>>(ei, row_ptr, epos, colA);
  k_sort   <<<(N_NODES + 3) / 4, 256, 0, stream>>>(row_ptr, colA);
  k_wt     <<<128, 256, 0, stream>>>(W1l, W1r, Wt);
  k_gemm1  <<<(N_NODES + 63) / 64, 256, 0, stream>>>(x, Wt, Hlb, Hrb);
  k_agg1   <<<(N_NODES + 15) / 16, 256, 0, stream>>>(Hlb, Hrb, row_ptr, colA, att1, b1, W2l, W2r, yl, yr);
  k_agg2   <<<(N_NODES + 15) / 16, 256, 0, stream>>>(yl, yr, row_ptr, colA, att2, b2, out);
}

// Round 11
// 529.504 us; speedup vs baseline: 1.5043x; 1.5043x over previous
//
#include <hip/hip_runtime.h>

#define N_NODES 100000
#define E_EDGES 1600000
#define E_TOT   1700000   // edges + self loops
#define FDIM    128       // F_IN and HEADS*HID
#define C2      10        // classes
#define YPAD    16        // yl/yr row stride (one 64B line)
#define NEG     0.2f
#define LOG2E   1.44269504088896f
#define PCLAMP  80.0f

typedef __attribute__((ext_vector_type(8))) short short8;
typedef __attribute__((ext_vector_type(4))) float f32x4;

// 16-lane row reduction via DPP (pure VALU, no LDS pipe)
template <int CTRL>
__device__ __forceinline__ float dpp_add(float x) {
  return x + __int_as_float(
      __builtin_amdgcn_update_dpp(0, __float_as_int(x), CTRL, 0xF, 0xF, true));
}
__device__ __forceinline__ float row16_sum(float p) {
  p = dpp_add<0xB1>(p);
  p = dpp_add<0x4E>(p);
  p = dpp_add<0x141>(p);
  p = dpp_add<0x140>(p);
  return p;
}

// fp32 -> bf16 (round-nearest-even), and packed bf16x2 -> float2
__device__ __forceinline__ unsigned short f2bf(float f) {
  unsigned int u = __float_as_uint(f);
  u += 0x7FFFu + ((u >> 16) & 1u);
  return (unsigned short)(u >> 16);
}
__device__ __forceinline__ float2 up2(unsigned int v) {
  return make_float2(__uint_as_float(v << 16), __uint_as_float(v & 0xFFFF0000u));
}

// ---------------- CSR build ----------------
__global__ __launch_bounds__(256) void k_deg(const int* __restrict__ ei, int* __restrict__ cnt,
                                             int* __restrict__ epos) {
  int tid = blockIdx.x * 256 + threadIdx.x;
  if (tid >= E_TOT) return;
  int d = (tid < E_EDGES) ? ei[E_EDGES + tid] : (tid - E_EDGES);
  epos[tid] = atomicAdd(&cnt[d], 1);
}

#define SCAN_ITEMS 8
#define SCAN_CHUNK 2048
#define SCAN_NBLK  ((N_NODES + SCAN_CHUNK - 1) / SCAN_CHUNK)   // 49

__global__ __launch_bounds__(256) void k_scan1(const int* __restrict__ cnt, int* __restrict__ bsum) {
  int b = blockIdx.x, t = threadIdx.x;
  int base = b * SCAN_CHUNK + t * SCAN_ITEMS;
  int s = 0;
#pragma unroll
  for (int i = 0; i < SCAN_ITEMS; i++) {
    int idx = base + i;
    if (idx < N_NODES) s += cnt[idx];
  }
  __shared__ int sd[256];
  sd[t] = s; __syncthreads();
  for (int o = 128; o > 0; o >>= 1) {
    if (t < o) sd[t] += sd[t + o];
    __syncthreads();
  }
  if (t == 0) bsum[b] = sd[0];
}

__global__ __launch_bounds__(64) void k_scan2(const int* __restrict__ bsum, int* __restrict__ boff) {
  int t = threadIdx.x;
  int v = (t < SCAN_NBLK) ? bsum[t] : 0;
  int orig = v;
  for (int o = 1; o < 64; o <<= 1) {
    int u = __shfl_up(v, o);
    if (t >= o) v += u;
  }
  if (t < SCAN_NBLK) boff[t] = v - orig;
}

__global__ __launch_bounds__(256) void k_scan3(const int* __restrict__ cnt, const int* __restrict__ boff,
                                               int* __restrict__ row_ptr) {
  int b = blockIdx.x, t = threadIdx.x;
  int base = b * SCAN_CHUNK + t * SCAN_ITEMS;
  int vals[SCAN_ITEMS]; int ts = 0;
#pragma unroll
  for (int i = 0; i < SCAN_ITEMS; i++) {
    int idx = base + i;
    vals[i] = (idx < N_NODES) ? cnt[idx] : 0;
    ts += vals[i];
  }
  __shared__ int sd[256];
  sd[t] = ts; __syncthreads();
  for (int o = 1; o < 256; o <<= 1) {
    int v = 0;
    if (t >= o) v = sd[t - o];
    __syncthreads();
    sd[t] += v;
    __syncthreads();
  }
  int run = boff[b] + sd[t] - ts;
#pragma unroll
  for (int i = 0; i < SCAN_ITEMS; i++) {
    int idx = base + i;
    if (idx < N_NODES) row_ptr[idx] = run;
    run += vals[i];
  }
  if (b == 0 && t == 0) row_ptr[N_NODES] = E_TOT;
}

__global__ __launch_bounds__(256) void k_scatter(const int* __restrict__ ei,
                                                 const int* __restrict__ row_ptr,
                                                 const int* __restrict__ epos,
                                                 int* __restrict__ colA) {
  int tid = blockIdx.x * 256 + threadIdx.x;
  if (tid >= E_TOT) return;
  int s, d;
  if (tid < E_EDGES) { s = ei[tid]; d = ei[E_EDGES + tid]; }
  else { s = tid - E_EDGES; d = s; }
  colA[row_ptr[d] + epos[tid]] = s;
}

// Canonicalize CSR rows (deterministic FP accumulation order every call).
__global__ __launch_bounds__(256) void k_sort(const int* __restrict__ row_ptr, int* __restrict__ colA) {
  int node = blockIdx.x * 4 + (threadIdx.x >> 6);
  if (node >= N_NODES) return;
  int lane = threadIdx.x & 63;
  int beg = row_ptr[node], end = row_ptr[node + 1];
  int deg = end - beg;
  if (deg <= 1) return;
  if (deg <= 64) {
    int v = (lane < deg) ? colA[beg + lane] : 0x7FFFFFFF;
#pragma unroll
    for (int k = 2; k <= 64; k <<= 1) {
#pragma unroll
      for (int j = k >> 1; j > 0; j >>= 1) {
        int other = __shfl_xor(v, j);
        bool up = ((lane & k) == 0);
        bool lower = ((lane & j) == 0);
        int mn = min(v, other), mx = max(v, other);
        v = (lower == up) ? mn : mx;
      }
    }
    if (lane < deg) colA[beg + lane] = v;
  } else if (lane == 0) {
    for (int i = beg + 1; i < end; i++) {
      int v = colA[i];
      int j = i - 1;
      while (j >= beg && colA[j] > v) { colA[j + 1] = colA[j]; j--; }
      colA[j + 1] = v;
    }
  }
}

// ---------------- prep: W1l|W1r -> transposed bf16 [256][128] ----------------
__global__ __launch_bounds__(256) void k_wt(const float* __restrict__ W1l, const float* __restrict__ W1r,
                                            unsigned short* __restrict__ Wt) {
  int t = blockIdx.x * 256 + threadIdx.x;
  if (t >= 256 * 128) return;
  int n = t & 255, k = t >> 8;
  float v = (n < 128) ? W1l[k * 128 + n] : W1r[k * 128 + (n - 128)];
  Wt[n * 128 + k] = f2bf(v);   // B^T layout: row n, contiguous k
}

// ---------------- Layer-1 GEMM via MFMA: [Hl|Hr] = x @ [W1l|W1r] (bf16 in, fp32 acc) ----------------
__global__ __launch_bounds__(256) void k_gemm1(const float* __restrict__ x,
                                               const unsigned short* __restrict__ Wt,
                                               unsigned short* __restrict__ Hlb,
                                               unsigned short* __restrict__ Hrb) {
  int w = threadIdx.x >> 6, lane = threadIdx.x & 63;
  int m = lane & 15, quad = lane >> 4;
  int row0 = blockIdx.x * 64 + w * 16;
  int arow = row0 + m;
  short8 A[4];
  bool aok = arow < N_NODES;
  const float4* ap = (const float4*)(x + (size_t)arow * FDIM + quad * 8);
#pragma unroll
  for (int c = 0; c < 4; c++) {
    short8 a = {};
    if (aok) {
      float4 v0 = ap[c * 8 + 0];
      float4 v1 = ap[c * 8 + 1];
      a[0] = (short)f2bf(v0.x); a[1] = (short)f2bf(v0.y);
      a[2] = (short)f2bf(v0.z); a[3] = (short)f2bf(v0.w);
      a[4] = (short)f2bf(v1.x); a[5] = (short)f2bf(v1.y);
      a[6] = (short)f2bf(v1.z); a[7] = (short)f2bf(v1.w);
    }
    A[c] = a;
  }

  int orow = row0 + quad * 4;
#pragma unroll
  for (int t0 = 0; t0 < 16; t0++) {
    const short8* bp = (const short8*)(Wt + (size_t)(t0 * 16 + m) * 128 + quad * 8);
    f32x4 acc = {0.f, 0.f, 0.f, 0.f};
#pragma unroll
    for (int c = 0; c < 4; c++)
      acc = __builtin_amdgcn_mfma_f32_16x16x32_bf16(A[c], bp[c * 4], acc, 0, 0, 0);
    int n0 = t0 * 16;
    unsigned short* dst = (n0 < 128) ? Hlb : Hrb;
    int col = (n0 < 128) ? n0 + m : (n0 - 128) + m;
#pragma unroll
    for (int r = 0; r < 4; r++) {
      int row = orow + r;
      if (row < N_NODES) dst[(size_t)row * FDIM + col] = f2bf(acc[r]);
    }
  }
}

// ---------------- Layer-1 aggregation + fused layer-2 transform ----------------
// R9 structure (the measured optimum): 1 wave/node, 8-deep gather batches,
// VGPR=32, no spill. R10's deeper pipeline spilled to scratch and regressed.
__global__ __launch_bounds__(256) void k_agg1(const unsigned short* __restrict__ Hlb,
                                              const unsigned short* __restrict__ Hrb,
                                              const int* __restrict__ row_ptr, const int* __restrict__ colA,
                                              const float* __restrict__ att, const float* __restrict__ bias,
                                              const float* __restrict__ W2l, const float* __restrict__ W2r,
                                              float* __restrict__ yl, float* __restrict__ yr) {
  __shared__ float hsh[4][FDIM];
  int w = threadIdx.x >> 6;
  int node = blockIdx.x * 4 + w;
  if (node >= N_NODES) return;
  int lane = threadIdx.x & 63;
  int c0 = 2 * lane;
  const unsigned int* Hl32 = (const unsigned int*)Hlb;   // row = 64 uints
  const unsigned int* Hr32 = (const unsigned int*)Hrb;
  float2 xr = up2(Hr32[((size_t)node << 6) + lane]);
  float a0 = att[c0] * LOG2E;
  float a1 = att[c0 + 1] * LOG2E;
  int beg = row_ptr[node], end = row_ptr[node + 1];
  float l = 0.f, ax = 0.f, ay = 0.f;

  auto update = [&](unsigned int v) {
    float2 xl = up2(v);
    float tx = xl.x + xr.x, ty = xl.y + xr.y;
    tx = tx > 0.f ? tx : NEG * tx;
    ty = ty > 0.f ? ty : NEG * ty;
    float p = row16_sum(fmaf(a0, tx, a1 * ty));
    float ww = __builtin_amdgcn_exp2f(fminf(p, PCLAMP));
    l  += ww;
    ax = fmaf(ww, xl.x, ax);
    ay = fmaf(ww, xl.y, ay);
  };

  int j = beg;
  for (; j + 8 <= end; j += 8) {
    unsigned int v0 = Hl32[((size_t)colA[j + 0] << 6) + lane];
    unsigned int v1 = Hl32[((size_t)colA[j + 1] << 6) + lane];
    unsigned int v2 = Hl32[((size_t)colA[j + 2] << 6) + lane];
    unsigned int v3 = Hl32[((size_t)colA[j + 3] << 6) + lane];
    unsigned int v4 = Hl32[((size_t)colA[j + 4] << 6) + lane];
    unsigned int v5 = Hl32[((size_t)colA[j + 5] << 6) + lane];
    unsigned int v6 = Hl32[((size_t)colA[j + 6] << 6) + lane];
    unsigned int v7 = Hl32[((size_t)colA[j + 7] << 6) + lane];
    update(v0); update(v1); update(v2); update(v3);
    update(v4); update(v5); update(v6); update(v7);
  }
  for (; j + 2 <= end; j += 2) {
    unsigned int v0 = Hl32[((size_t)colA[j + 0] << 6) + lane];
    unsigned int v1 = Hl32[((size_t)colA[j + 1] << 6) + lane];
    update(v0); update(v1);
  }
  if (j < end) {
    update(Hl32[((size_t)colA[j] << 6) + lane]);
  }

  float inv = 1.f / l;
  float ox = fmaxf(fmaf(ax, inv, bias[c0]),     0.f);   // fused ReLU
  float oy = fmaxf(fmaf(ay, inv, bias[c0 + 1]), 0.f);
  hsh[w][c0] = ox; hsh[w][c0 + 1] = oy;
  if (lane < 2 * C2) {
    bool isl = lane < C2;
    int cc = isl ? lane : lane - C2;
    const float* W = isl ? W2l : W2r;
    float acc = 0.f;
    const float4* h4 = (const float4*)hsh[w];
#pragma unroll
    for (int k4 = 0; k4 < 32; k4++) {
      float4 hv = h4[k4];
      int k = k4 * 4;
      acc = fmaf(hv.x, W[(k + 0) * C2 + cc], acc);
      acc = fmaf(hv.y, W[(k + 1) * C2 + cc], acc);
      acc = fmaf(hv.z, W[(k + 2) * C2 + cc], acc);
      acc = fmaf(hv.w, W[(k + 3) * C2 + cc], acc);
    }
    float* Y = isl ? yl : yr;
    Y[(size_t)node * YPAD + cc] = acc;
  }
}

// ---------------- Layer-2 aggregation: 16-lane group per node ----------------
__global__ __launch_bounds__(256) void k_agg2(const float* __restrict__ yl, const float* __restrict__ yr,
                                              const int* __restrict__ row_ptr, const int* __restrict__ colA,
                                              const float* __restrict__ att, const float* __restrict__ bias,
                                              float* __restrict__ outp) {
  int node = blockIdx.x * 16 + (threadIdx.x >> 4);
  if (node >= N_NODES) return;
  int lane = threadIdx.x & 15;
  bool act = lane < C2;
  float xr = act ? yr[(size_t)node * YPAD + lane] : 0.f;
  float a  = act ? att[lane] * LOG2E : 0.f;
  int beg = row_ptr[node], end = row_ptr[node + 1];
  float l = 0.f, acc = 0.f;
  const float* ylL = yl + (act ? lane : 0);

  auto update = [&](float xl) {
    float t = xl + xr;
    t = t > 0.f ? t : NEG * t;
    float p = row16_sum(a * t);
    float w = __builtin_amdgcn_exp2f(fminf(p, PCLAMP));
    l += w;
    acc = fmaf(w, xl, acc);
  };

  int j = beg;
  for (; j + 8 <= end; j += 8) {
    float x0 = act ? ylL[(size_t)colA[j + 0] << 4] : 0.f;
    float x1 = act ? ylL[(size_t)colA[j + 1] << 4] : 0.f;
    float x2 = act ? ylL[(size_t)colA[j + 2] << 4] : 0.f;
    float x3 = act ? ylL[(size_t)colA[j + 3] << 4] : 0.f;
    float x4 = act ? ylL[(size_t)colA[j + 4] << 4] : 0.f;
    float x5 = act ? ylL[(size_t)colA[j + 5] << 4] : 0.f;
    float x6 = act ? ylL[(size_t)colA[j + 6] << 4] : 0.f;
    float x7 = act ? ylL[(size_t)colA[j + 7] << 4] : 0.f;
    update(x0); update(x1); update(x2); update(x3);
    update(x4); update(x5); update(x6); update(x7);
  }
  for (; j < end; j++) {
    float x0 = act ? ylL[(size_t)colA[j] << 4] : 0.f;
    update(x0);
  }
  if (act) outp[(size_t)node * C2 + lane] = acc / l + bias[lane];
}

extern "C" void kernel_launch(void* const* d_in, const int* in_sizes, int n_in,
                              void* d_out, int out_size, void* d_ws, size_t ws_size,
                              hipStream_t stream) {
  const float* x    = (const float*)d_in[0];
  const int*   ei   = (const int*)d_in[1];
  const float* W1l  = (const float*)d_in[2];
  const float* W1r  = (const float*)d_in[3];
  const float* att1 = (const float*)d_in[4];
  const float* b1   = (const float*)d_in[5];
  const float* W2l  = (const float*)d_in[6];
  const float* W2r  = (const float*)d_in[7];
  const float* att2 = (const float*)d_in[8];
  const float* b2   = (const float*)d_in[9];
  float* out = (float*)d_out;

  char* ws = (char*)d_ws;
  size_t off = 0;
  auto take = [&](size_t bytes) -> char* {
    char* p = ws + off;
    off = (off + bytes + 511) & ~(size_t)511;
    return p;
  };
  unsigned short* Hlb = (unsigned short*)take((size_t)N_NODES * FDIM * sizeof(unsigned short)); // 25.6 MB
  unsigned short* Hrb = (unsigned short*)take((size_t)N_NODES * FDIM * sizeof(unsigned short)); // 25.6 MB
  unsigned short* Wt  = (unsigned short*)take((size_t)256 * 128 * sizeof(unsigned short));      // 64 KB
  float* yl      = (float*)take((size_t)N_NODES * YPAD * sizeof(float));   // 6.4 MB
  float* yr      = (float*)take((size_t)N_NODES * YPAD * sizeof(float));   // 6.4 MB
  int*   cnt     = (int*)take((size_t)N_NODES * sizeof(int));
  int*   row_ptr = (int*)take((size_t)(N_NODES + 1) * sizeof(int));
  int*   colA    = (int*)take((size_t)E_TOT * sizeof(int));
  int*   epos    = (int*)take((size_t)E_TOT * sizeof(int));
  int*   bsum    = (int*)take(256);
  int*   boff    = (int*)take(256);
  if (off > ws_size) return;

  (void)hipMemsetAsync(cnt, 0, (size_t)N_NODES * sizeof(int), stream);
  k_deg    <<<(E_TOT + 255) / 256, 256, 0, stream>>>(ei, cnt, epos);
  k_scan1  <<<SCAN_NBLK, 256, 0, stream>>>(cnt, bsum);
  k_scan2  <<<1, 64, 0, stream>>>(bsum, boff);
  k_scan3  <<<SCAN_NBLK, 256, 0, stream>>>(cnt, boff, row_ptr);
  k_scatter<<<(E_TOT + 255) / 256, 256, 0, stream>>>(ei, row_ptr, epos, colA);
  k_sort   <<<(N_NODES + 3) / 4, 256, 0, stream>>>(row_ptr, colA);
  k_wt     <<<128, 256, 0, stream>>>(W1l, W1r, Wt);
  k_gemm1  <<<(N_NODES + 63) / 64, 256, 0, stream>>>(x, Wt, Hlb, Hrb);
  k_agg1   <<<(N_NODES + 3) / 4, 256, 0, stream>>>(Hlb, Hrb, row_ptr, colA, att1, b1, W2l, W2r, yl, yr);
  k_agg2   <<<(N_NODES + 15) / 16, 256, 0, stream>>>(yl, yr, row_ptr, colA, att2, b2, out);
}

// Round 12
// 507.758 us; speedup vs baseline: 1.5688x; 1.0428x over previous
//
#include <hip/hip_runtime.h>

#define N_NODES 100000
#define E_EDGES 1600000
#define E_TOT   1700000   // edges + self loops
#define FDIM    128       // F_IN and HEADS*HID
#define C2      10        // classes
#define YPAD    16        // yl/yr row stride (one 64B line)
#define NEG     0.2f
#define LOG2E   1.44269504088896f
#define PCLAMP  80.0f

typedef __attribute__((ext_vector_type(8))) short short8;
typedef __attribute__((ext_vector_type(4))) float f32x4;

// 16-lane row reduction via DPP (pure VALU, no LDS pipe)
template <int CTRL>
__device__ __forceinline__ float dpp_add(float x) {
  return x + __int_as_float(
      __builtin_amdgcn_update_dpp(0, __float_as_int(x), CTRL, 0xF, 0xF, true));
}
__device__ __forceinline__ float row16_sum(float p) {
  p = dpp_add<0xB1>(p);
  p = dpp_add<0x4E>(p);
  p = dpp_add<0x141>(p);
  p = dpp_add<0x140>(p);
  return p;
}

// fp32 -> bf16 (round-nearest-even), and packed bf16x2 -> float2
__device__ __forceinline__ unsigned short f2bf(float f) {
  unsigned int u = __float_as_uint(f);
  u += 0x7FFFu + ((u >> 16) & 1u);
  return (unsigned short)(u >> 16);
}
__device__ __forceinline__ float2 up2(unsigned int v) {
  return make_float2(__uint_as_float(v << 16), __uint_as_float(v & 0xFFFF0000u));
}

// ---------------- CSR build ----------------
__global__ __launch_bounds__(256) void k_deg(const int* __restrict__ ei, int* __restrict__ cnt,
                                             int* __restrict__ epos) {
  int tid = blockIdx.x * 256 + threadIdx.x;
  if (tid >= E_TOT) return;
  int d = (tid < E_EDGES) ? ei[E_EDGES + tid] : (tid - E_EDGES);
  epos[tid] = atomicAdd(&cnt[d], 1);
}

#define SCAN_ITEMS 8
#define SCAN_CHUNK 2048
#define SCAN_NBLK  ((N_NODES + SCAN_CHUNK - 1) / SCAN_CHUNK)   // 49

__global__ __launch_bounds__(256) void k_scan1(const int* __restrict__ cnt, int* __restrict__ bsum) {
  int b = blockIdx.x, t = threadIdx.x;
  int base = b * SCAN_CHUNK + t * SCAN_ITEMS;
  int s = 0;
#pragma unroll
  for (int i = 0; i < SCAN_ITEMS; i++) {
    int idx = base + i;
    if (idx < N_NODES) s += cnt[idx];
  }
  __shared__ int sd[256];
  sd[t] = s; __syncthreads();
  for (int o = 128; o > 0; o >>= 1) {
    if (t < o) sd[t] += sd[t + o];
    __syncthreads();
  }
  if (t == 0) bsum[b] = sd[0];
}

__global__ __launch_bounds__(64) void k_scan2(const int* __restrict__ bsum, int* __restrict__ boff) {
  int t = threadIdx.x;
  int v = (t < SCAN_NBLK) ? bsum[t] : 0;
  int orig = v;
  for (int o = 1; o < 64; o <<= 1) {
    int u = __shfl_up(v, o);
    if (t >= o) v += u;
  }
  if (t < SCAN_NBLK) boff[t] = v - orig;
}

__global__ __launch_bounds__(256) void k_scan3(const int* __restrict__ cnt, const int* __restrict__ boff,
                                               int* __restrict__ row_ptr) {
  int b = blockIdx.x, t = threadIdx.x;
  int base = b * SCAN_CHUNK + t * SCAN_ITEMS;
  int vals[SCAN_ITEMS]; int ts = 0;
#pragma unroll
  for (int i = 0; i < SCAN_ITEMS; i++) {
    int idx = base + i;
    vals[i] = (idx < N_NODES) ? cnt[idx] : 0;
    ts += vals[i];
  }
  __shared__ int sd[256];
  sd[t] = ts; __syncthreads();
  for (int o = 1; o < 256; o <<= 1) {
    int v = 0;
    if (t >= o) v = sd[t - o];
    __syncthreads();
    sd[t] += v;
    __syncthreads();
  }
  int run = boff[b] + sd[t] - ts;
#pragma unroll
  for (int i = 0; i < SCAN_ITEMS; i++) {
    int idx = base + i;
    if (idx < N_NODES) row_ptr[idx] = run;
    run += vals[i];
  }
  if (b == 0 && t == 0) row_ptr[N_NODES] = E_TOT;
}

__global__ __launch_bounds__(256) void k_scatter(const int* __restrict__ ei,
                                                 const int* __restrict__ row_ptr,
                                                 const int* __restrict__ epos,
                                                 int* __restrict__ colA) {
  int tid = blockIdx.x * 256 + threadIdx.x;
  if (tid >= E_TOT) return;
  int s, d;
  if (tid < E_EDGES) { s = ei[tid]; d = ei[E_EDGES + tid]; }
  else { s = tid - E_EDGES; d = s; }
  colA[row_ptr[d] + epos[tid]] = s;
}

// ---------------- prep: W1l|W1r -> transposed bf16 [256][128] ----------------
__global__ __launch_bounds__(256) void k_wt(const float* __restrict__ W1l, const float* __restrict__ W1r,
                                            unsigned short* __restrict__ Wt) {
  int t = blockIdx.x * 256 + threadIdx.x;
  if (t >= 256 * 128) return;
  int n = t & 255, k = t >> 8;
  float v = (n < 128) ? W1l[k * 128 + n] : W1r[k * 128 + (n - 128)];
  Wt[n * 128 + k] = f2bf(v);   // B^T layout: row n, contiguous k
}

// ---------------- Layer-1 GEMM via MFMA: [Hl|Hr] = x @ [W1l|W1r] (bf16 in, fp32 acc) ----------------
__global__ __launch_bounds__(256) void k_gemm1(const float* __restrict__ x,
                                               const unsigned short* __restrict__ Wt,
                                               unsigned short* __restrict__ Hlb,
                                               unsigned short* __restrict__ Hrb) {
  int w = threadIdx.x >> 6, lane = threadIdx.x & 63;
  int m = lane & 15, quad = lane >> 4;
  int row0 = blockIdx.x * 64 + w * 16;
  int arow = row0 + m;
  short8 A[4];
  bool aok = arow < N_NODES;
  const float4* ap = (const float4*)(x + (size_t)arow * FDIM + quad * 8);
#pragma unroll
  for (int c = 0; c < 4; c++) {
    short8 a = {};
    if (aok) {
      float4 v0 = ap[c * 8 + 0];
      float4 v1 = ap[c * 8 + 1];
      a[0] = (short)f2bf(v0.x); a[1] = (short)f2bf(v0.y);
      a[2] = (short)f2bf(v0.z); a[3] = (short)f2bf(v0.w);
      a[4] = (short)f2bf(v1.x); a[5] = (short)f2bf(v1.y);
      a[6] = (short)f2bf(v1.z); a[7] = (short)f2bf(v1.w);
    }
    A[c] = a;
  }

  int orow = row0 + quad * 4;
#pragma unroll
  for (int t0 = 0; t0 < 16; t0++) {
    const short8* bp = (const short8*)(Wt + (size_t)(t0 * 16 + m) * 128 + quad * 8);
    f32x4 acc = {0.f, 0.f, 0.f, 0.f};
#pragma unroll
    for (int c = 0; c < 4; c++)
      acc = __builtin_amdgcn_mfma_f32_16x16x32_bf16(A[c], bp[c * 4], acc, 0, 0, 0);
    int n0 = t0 * 16;
    unsigned short* dst = (n0 < 128) ? Hlb : Hrb;
    int col = (n0 < 128) ? n0 + m : (n0 - 128) + m;
#pragma unroll
    for (int r = 0; r < 4; r++) {
      int row = orow + r;
      if (row < N_NODES) dst[(size_t)row * FDIM + col] = f2bf(acc[r]);
    }
  }
}

// ---------------- Layer-1 aggregation + in-wave CSR sort + fused layer-2 transform ----------------
// R9 gather structure (1 wave/node, 8-deep batches, VGPR~32). New: the wave
// bitonic-sorts its row into LDS first (hides in gather stalls), consumes idx
// from LDS, and writes the sorted row back to colA for agg2. k_sort kernel gone.
__global__ __launch_bounds__(256) void k_agg1(const unsigned short* __restrict__ Hlb,
                                              const unsigned short* __restrict__ Hrb,
                                              const int* __restrict__ row_ptr, int* __restrict__ colA,
                                              const float* __restrict__ att, const float* __restrict__ bias,
                                              const float* __restrict__ W2l, const float* __restrict__ W2r,
                                              float* __restrict__ yl, float* __restrict__ yr) {
  __shared__ float hsh[4][FDIM];
  __shared__ int sidx[4][64];
  int w = threadIdx.x >> 6;
  int node = blockIdx.x * 4 + w;
  if (node >= N_NODES) return;
  int lane = threadIdx.x & 63;
  int c0 = 2 * lane;
  const unsigned int* Hl32 = (const unsigned int*)Hlb;   // row = 64 uints
  const unsigned int* Hr32 = (const unsigned int*)Hrb;
  float2 xr = up2(Hr32[((size_t)node << 6) + lane]);
  float a0 = att[c0] * LOG2E;
  float a1 = att[c0 + 1] * LOG2E;
  int beg = row_ptr[node], end = row_ptr[node + 1];
  int deg = end - beg;
  bool small = deg <= 64;

  if (small) {
    // in-wave bitonic sort (canonical ascending order -> deterministic FP order)
    int v = (lane < deg) ? colA[beg + lane] : 0x7FFFFFFF;
#pragma unroll
    for (int k = 2; k <= 64; k <<= 1) {
#pragma unroll
      for (int j = k >> 1; j > 0; j >>= 1) {
        int other = __shfl_xor(v, j);
        bool up = ((lane & k) == 0);
        bool lower = ((lane & j) == 0);
        int mn = min(v, other), mx = max(v, other);
        v = (lower == up) ? mn : mx;
      }
    }
    sidx[w][lane] = v;                      // intra-wave: DS ops in order
    if (lane < deg) colA[beg + lane] = v;   // sorted row for agg2
  } else {
    // ~never at avg degree 17; lane-0 insertion sort in global, then fence
    if (lane == 0) {
      for (int i = beg + 1; i < end; i++) {
        int vv = colA[i];
        int j = i - 1;
        while (j >= beg && colA[j] > vv) { colA[j + 1] = colA[j]; j--; }
        colA[j + 1] = vv;
      }
    }
    __threadfence_block();
  }

  float l = 0.f, ax = 0.f, ay = 0.f;
  auto update = [&](unsigned int v) {
    float2 xl = up2(v);
    float tx = xl.x + xr.x, ty = xl.y + xr.y;
    tx = tx > 0.f ? tx : NEG * tx;
    ty = ty > 0.f ? ty : NEG * ty;
    float p = row16_sum(fmaf(a0, tx, a1 * ty));
    float ww = __builtin_amdgcn_exp2f(fminf(p, PCLAMP));
    l  += ww;
    ax = fmaf(ww, xl.x, ax);
    ay = fmaf(ww, xl.y, ay);
  };

  if (small) {
    const int* si = sidx[w];
    int j = 0;
    for (; j + 8 <= deg; j += 8) {
      unsigned int v0 = Hl32[((size_t)si[j + 0] << 6) + lane];
      unsigned int v1 = Hl32[((size_t)si[j + 1] << 6) + lane];
      unsigned int v2 = Hl32[((size_t)si[j + 2] << 6) + lane];
      unsigned int v3 = Hl32[((size_t)si[j + 3] << 6) + lane];
      unsigned int v4 = Hl32[((size_t)si[j + 4] << 6) + lane];
      unsigned int v5 = Hl32[((size_t)si[j + 5] << 6) + lane];
      unsigned int v6 = Hl32[((size_t)si[j + 6] << 6) + lane];
      unsigned int v7 = Hl32[((size_t)si[j + 7] << 6) + lane];
      update(v0); update(v1); update(v2); update(v3);
      update(v4); update(v5); update(v6); update(v7);
    }
    for (; j + 2 <= deg; j += 2) {
      unsigned int v0 = Hl32[((size_t)si[j + 0] << 6) + lane];
      unsigned int v1 = Hl32[((size_t)si[j + 1] << 6) + lane];
      update(v0); update(v1);
    }
    if (j < deg) update(Hl32[((size_t)si[j] << 6) + lane]);
  } else {
    for (int j = beg; j < end; j++) update(Hl32[((size_t)colA[j] << 6) + lane]);
  }

  float inv = 1.f / l;
  float ox = fmaxf(fmaf(ax, inv, bias[c0]),     0.f);   // fused ReLU
  float oy = fmaxf(fmaf(ay, inv, bias[c0 + 1]), 0.f);
  hsh[w][c0] = ox; hsh[w][c0 + 1] = oy;
  if (lane < 2 * C2) {
    bool isl = lane < C2;
    int cc = isl ? lane : lane - C2;
    const float* W = isl ? W2l : W2r;
    float acc = 0.f;
    const float4* h4 = (const float4*)hsh[w];
#pragma unroll
    for (int k4 = 0; k4 < 32; k4++) {
      float4 hv = h4[k4];
      int k = k4 * 4;
      acc = fmaf(hv.x, W[(k + 0) * C2 + cc], acc);
      acc = fmaf(hv.y, W[(k + 1) * C2 + cc], acc);
      acc = fmaf(hv.z, W[(k + 2) * C2 + cc], acc);
      acc = fmaf(hv.w, W[(k + 3) * C2 + cc], acc);
    }
    float* Y = isl ? yl : yr;
    Y[(size_t)node * YPAD + cc] = acc;
  }
}

// ---------------- Layer-2 aggregation: 1 wave/node, 4-way edge-parallel ----------------
// No-max softmax => (l, acc) are plain sums: any FIXED partition/tree is
// deterministic. Group g (lanes 16g..16g+15) handles edges j===g (mod 4) in
// ascending order; fixed combine tree via shfl_xor(16), shfl_xor(32).
__global__ __launch_bounds__(256) void k_agg2(const float* __restrict__ yl, const float* __restrict__ yr,
                                              const int* __restrict__ row_ptr, const int* __restrict__ colA,
                                              const float* __restrict__ att, const float* __restrict__ bias,
                                              float* __restrict__ outp) {
  int w = threadIdx.x >> 6;
  int node = blockIdx.x * 4 + w;
  if (node >= N_NODES) return;
  int lane = threadIdx.x & 63;
  int ch = lane & 15;
  int g  = lane >> 4;
  bool act = ch < C2;
  float xr = act ? yr[(size_t)node * YPAD + ch] : 0.f;
  float a  = act ? att[ch] * LOG2E : 0.f;
  int beg = row_ptr[node], end = row_ptr[node + 1];
  float l = 0.f, acc = 0.f;
  const float* ylL = yl + (act ? ch : 0);

  auto update = [&](float xl) {
    float t = xl + xr;
    t = t > 0.f ? t : NEG * t;
    float p = row16_sum(a * t);                 // 16-lane group reduce
    float wgt = __builtin_amdgcn_exp2f(fminf(p, PCLAMP));
    l += wgt;
    acc = fmaf(wgt, xl, acc);
  };

  int j = beg + g;
  for (; j + 4 < end; j += 8) {                 // 2 edges of this group: j, j+4
    int s0 = colA[j], s1 = colA[j + 4];
    float x0 = act ? ylL[(size_t)s0 << 4] : 0.f;
    float x1 = act ? ylL[(size_t)s1 << 4] : 0.f;
    update(x0); update(x1);
  }
  if (j < end) {
    int s0 = colA[j];
    float x0 = act ? ylL[(size_t)s0 << 4] : 0.f;
    update(x0);
  }

  // fixed combine tree across groups (deterministic): (g0+g1)+(g2+g3)
  l   += __shfl_xor(l, 16);
  acc += __shfl_xor(acc, 16);
  l   += __shfl_xor(l, 32);
  acc += __shfl_xor(acc, 32);
  if (g == 0 && act) outp[(size_t)node * C2 + ch] = acc / l + bias[ch];
}

extern "C" void kernel_launch(void* const* d_in, const int* in_sizes, int n_in,
                              void* d_out, int out_size, void* d_ws, size_t ws_size,
                              hipStream_t stream) {
  const float* x    = (const float*)d_in[0];
  const int*   ei   = (const int*)d_in[1];
  const float* W1l  = (const float*)d_in[2];
  const float* W1r  = (const float*)d_in[3];
  const float* att1 = (const float*)d_in[4];
  const float* b1   = (const float*)d_in[5];
  const float* W2l  = (const float*)d_in[6];
  const float* W2r  = (const float*)d_in[7];
  const float* att2 = (const float*)d_in[8];
  const float* b2   = (const float*)d_in[9];
  float* out = (float*)d_out;

  char* ws = (char*)d_ws;
  size_t off = 0;
  auto take = [&](size_t bytes) -> char* {
    char* p = ws + off;
    off = (off + bytes + 511) & ~(size_t)511;
    return p;
  };
  unsigned short* Hlb = (unsigned short*)take((size_t)N_NODES * FDIM * sizeof(unsigned short)); // 25.6 MB
  unsigned short* Hrb = (unsigned short*)take((size_t)N_NODES * FDIM * sizeof(unsigned short)); // 25.6 MB
  unsigned short* Wt  = (unsigned short*)take((size_t)256 * 128 * sizeof(unsigned short));      // 64 KB
  float* yl      = (float*)take((size_t)N_NODES * YPAD * sizeof(float));   // 6.4 MB
  float* yr      = (float*)take((size_t)N_NODES * YPAD * sizeof(float));   // 6.4 MB
  int*   cnt     = (int*)take((size_t)N_NODES * sizeof(int));
  int*   row_ptr = (int*)take((size_t)(N_NODES + 1) * sizeof(int));
  int*   colA    = (int*)take((size_t)E_TOT * sizeof(int));
  int*   epos    = (int*)take((size_t)E_TOT * sizeof(int));
  int*   bsum    = (int*)take(256);
  int*   boff    = (int*)take(256);
  if (off > ws_size) return;

  (void)hipMemsetAsync(cnt, 0, (size_t)N_NODES * sizeof(int), stream);
  k_deg    <<<(E_TOT + 255) / 256, 256, 0, stream>>>(ei, cnt, epos);
  k_scan1  <<<SCAN_NBLK, 256, 0, stream>>>(cnt, bsum);
  k_scan2  <<<1, 64, 0, stream>>>(bsum, boff);
  k_scan3  <<<SCAN_NBLK, 256, 0, stream>>>(cnt, boff, row_ptr);
  k_scatter<<<(E_TOT + 255) / 256, 256, 0, stream>>>(ei, row_ptr, epos, colA);
  k_wt     <<<128, 256, 0, stream>>>(W1l, W1r, Wt);
  k_gemm1  <<<(N_NODES + 63) / 64, 256, 0, stream>>>(x, Wt, Hlb, Hrb);
  k_agg1   <<<(N_NODES + 3) / 4, 256, 0, stream>>>(Hlb, Hrb, row_ptr, colA, att1, b1, W2l, W2r, yl, yr);
  k_agg2   <<<(N_NODES + 3) / 4, 256, 0, stream>>>(yl, yr, row_ptr, colA, att2, b2, out);
}